// Round 17
// baseline (78.758 us; speedup 1.0000x reference)
//
#include <hip/hip_runtime.h>
#include <hip/hip_bf16.h>
#include <hip/hip_cooperative_groups.h>
#include <math.h>

namespace cg = cooperative_groups;

#define H_N 16
#define DH 64
#define LSEQ 1024
#define BATCH 2
#define NSLOT 2048
#define DMODEL 1024

typedef __bf16 bf16x8 __attribute__((ext_vector_type(8)));
typedef __bf16 bf16x4 __attribute__((ext_vector_type(4)));
typedef float f32x4 __attribute__((ext_vector_type(4)));

// ---------- templated MFMA GEMM core, double-buffered LDS, parametric BK ----------
template <int BM, int BN, int BK>
__device__ __forceinline__ void gemm_coreT(const __bf16* __restrict__ A,
                                           const __bf16* __restrict__ Bm,
                                           int K, int m0, int n0,
                                           __bf16* As, __bf16* Bs,
                                           f32x4 acc[BM / 32][BN / 32],
                                           int tid, int wr, int wc, int lane) {
    constexpr int MF = BM / 32, NF = BN / 32;
    constexpr int SLOTS = BK / 8;
    constexpr int RPI = 256 / SLOTS;
    constexpr int AIT = BM / RPI;
    constexpr int BIT = BN / RPI;
    const f32x4 z = {0.f, 0.f, 0.f, 0.f};
#pragma unroll
    for (int m = 0; m < MF; ++m)
#pragma unroll
        for (int n = 0; n < NF; ++n) acc[m][n] = z;

    const int l15 = lane & 15, g = lane >> 4;
    const int wv = tid >> 6;
    const int srow = tid / SLOTS, sslot = tid % SLOTS;
    const int ssrc = (sslot ^ (srow & 7)) * 8;

#pragma unroll
    for (int i = 0; i < AIT; ++i) {
        int row = i * RPI + srow;
        __builtin_amdgcn_global_load_lds(
            (const __attribute__((address_space(1))) void*)(A + (size_t)(m0 + row) * K + ssrc),
            (__attribute__((address_space(3))) void*)(As + i * 2048 + wv * 512), 16, 0, 0);
    }
#pragma unroll
    for (int i = 0; i < BIT; ++i) {
        int row = i * RPI + srow;
        __builtin_amdgcn_global_load_lds(
            (const __attribute__((address_space(1))) void*)(Bm + (size_t)(n0 + row) * K + ssrc),
            (__attribute__((address_space(3))) void*)(Bs + i * 2048 + wv * 512), 16, 0, 0);
    }
    __syncthreads();

    const int NT = K / BK;
    for (int t = 0; t < NT; ++t) {
        const int cur = t & 1;
        __bf16* Ac = As + cur * (BM * BK);
        __bf16* Bc = Bs + cur * (BN * BK);
        if (t + 1 < NT) {
            const int k0 = (t + 1) * BK;
            __bf16* An = As + (1 - cur) * (BM * BK);
            __bf16* Bn = Bs + (1 - cur) * (BN * BK);
#pragma unroll
            for (int i = 0; i < AIT; ++i) {
                int row = i * RPI + srow;
                __builtin_amdgcn_global_load_lds(
                    (const __attribute__((address_space(1))) void*)(A + (size_t)(m0 + row) * K + k0 + ssrc),
                    (__attribute__((address_space(3))) void*)(An + i * 2048 + wv * 512), 16, 0, 0);
            }
#pragma unroll
            for (int i = 0; i < BIT; ++i) {
                int row = i * RPI + srow;
                __builtin_amdgcn_global_load_lds(
                    (const __attribute__((address_space(1))) void*)(Bm + (size_t)(n0 + row) * K + k0 + ssrc),
                    (__attribute__((address_space(3))) void*)(Bn + i * 2048 + wv * 512), 16, 0, 0);
            }
        }
        __builtin_amdgcn_s_setprio(1);
#pragma unroll
        for (int kk = 0; kk < BK / 32; ++kk) {
            const int k16 = kk * 4 + g;
            bf16x8 af[MF], bfr[NF];
#pragma unroll
            for (int m = 0; m < MF; ++m) {
                int row = wr * (BM / 2) + m * 16 + l15;
                int slot = k16 ^ (row & 7);
                af[m] = *reinterpret_cast<const bf16x8*>(Ac + row * BK + slot * 8);
            }
#pragma unroll
            for (int n = 0; n < NF; ++n) {
                int col = wc * (BN / 2) + n * 16 + l15;
                int slot = k16 ^ (col & 7);
                bfr[n] = *reinterpret_cast<const bf16x8*>(Bc + col * BK + slot * 8);
            }
#pragma unroll
            for (int m = 0; m < MF; ++m)
#pragma unroll
                for (int n = 0; n < NF; ++n)
                    acc[m][n] = __builtin_amdgcn_mfma_f32_16x16x32_bf16(af[m], bfr[n], acc[m][n], 0, 0, 0);
        }
        __builtin_amdgcn_s_setprio(0);
        __syncthreads();
    }
}

// ---------- shared device helpers ----------
__device__ __forceinline__ void setup_body(int blk, int tid,
                                           const float* x, const float* Wqkv, const float* Wproj,
                                           const float* topo, const float* Wfreq,
                                           __bf16* xb, __bf16* Wqkvb, __bf16* Wprojb,
                                           float* cosb, float* sinb) {
    if (blk < 6144) {
        const float* in;
        __bf16* ob;
        int base;
        if (blk < 2048)      { in = x;     ob = xb;     base = blk; }
        else if (blk < 5120) { in = Wqkv;  ob = Wqkvb;  base = blk - 2048; }
        else                 { in = Wproj; ob = Wprojb; base = blk - 5120; }
        int i = (base * 256 + tid) * 4;
        float4 v = *reinterpret_cast<const float4*>(in + i);
        struct B4 { __bf16 a, b, c, d; };
        B4 o{(__bf16)v.x, (__bf16)v.y, (__bf16)v.z, (__bf16)v.w};
        *reinterpret_cast<B4*>(ob + i) = o;
    } else {
        int s = (blk - 6144) * 8 + (tid >> 5);
        int j = tid & 31;
        float f = 0.f;
#pragma unroll
        for (int t = 0; t < 8; ++t) f += topo[s * 8 + t] * Wfreq[j * 8 + t];
        cosb[s * 32 + j] = cosf(f);
        sinb[s * 32 + j] = sinf(f);
    }
}

// 2-D XCD-chunked block mappings
__device__ __forceinline__ void qkv_map(int bid, int& m0, int& n0) {
    const int xcd = bid & 7, t = bid >> 3;
    m0 = ((xcd & 1) * 8 + (t & 7)) * 128;
    n0 = ((xcd >> 1) * 8 + (t >> 3)) * 96;
}
__device__ __forceinline__ void proj_map(int bid, int& m0, int& n0) {
    const int xcd = bid & 7, t = bid >> 3;
    m0 = ((xcd & 3) * 8 + (t & 7)) * 64;
    n0 = ((xcd >> 2) * 8 + (t >> 3)) * 64;
}

__device__ __forceinline__ void qkv_epilogue(f32x4 acc[4][3], int m0, int n0,
                                             int wr, int wc, int l15, int g,
                                             const float* cosb, const float* sinb,
                                             __bf16* Qb, __bf16* Kb, __bf16* Vtb) {
    const int rbase = m0 + wr * 64;
#pragma unroll
    for (int n = 0; n < 3; ++n) {
        int c = n0 + wc * 48 + n * 16 + l15;
        int part = c >> 10, h = (c >> 6) & 15, d = c & 63, jj = d >> 1;
#pragma unroll
        for (int m = 0; m < 4; ++m) {
            int sbase = rbase + m * 16 + g * 4;
            if (part < 2) {
                __bf16* dst = (part == 0) ? Qb : Kb;
#pragma unroll
                for (int j = 0; j < 4; ++j) {
                    int s = sbase + j;
                    float v = acc[m][n][j];
                    float partner = __shfl_xor(v, 1);
                    float cs = cosb[s * 32 + jj], sn = sinb[s * 32 + jj];
                    float outv = (d & 1) ? fmaf(v, cs, partner * sn) : fmaf(v, cs, -partner * sn);
                    dst[((size_t)h * NSLOT + s) * DH + d] = (__bf16)outv;
                }
            } else {
                bf16x4 pk;
#pragma unroll
                for (int j = 0; j < 4; ++j) pk[j] = (__bf16)acc[m][n][j];
                *reinterpret_cast<bf16x4*>(&Vtb[((size_t)h * DH + d) * NSLOT + sbase]) = pk;
            }
        }
    }
}

// attention chunk compute (KVBLK=128)
__device__ __forceinline__ void attn_chunk(const bf16x8 qf[2], __bf16* Kc, __bf16* Vc,
                                           __bf16* Pw, int ch, int nch, int q0,
                                           int l15, int g, f32x4 ao[4], float lsum[4]) {
    const f32x4 z = {0.f, 0.f, 0.f, 0.f};
    f32x4 s[8];
#pragma unroll
    for (int n = 0; n < 8; ++n) s[n] = z;
    __builtin_amdgcn_s_setprio(1);
#pragma unroll
    for (int g2 = 0; g2 < 2; ++g2) {
#pragma unroll
        for (int n = 0; n < 8; ++n) {
            int r = n * 16 + l15;
            int slot = ((g2 << 2) + g) ^ (r & 7);
            bf16x8 kf = *reinterpret_cast<const bf16x8*>(Kc + r * 64 + slot * 8);
            s[n] = __builtin_amdgcn_mfma_f32_16x16x32_bf16(qf[g2], kf, s[n], 0, 0, 0);
        }
    }
    __builtin_amdgcn_s_setprio(0);

    const bool last = (ch == nch - 1);
    const int sp0 = ch * 128;
#pragma unroll
    for (int n = 0; n < 8; ++n) {
        int key = sp0 + n * 16 + l15;
#pragma unroll
        for (int j = 0; j < 4; ++j) {
            float sc = s[n][j] * 0.125f;
            if (last && key > q0 + g * 4 + j) sc = -INFINITY;
            float p = __expf(sc);
            s[n][j] = p;
            lsum[j] += p;
        }
    }

#pragma unroll
    for (int j = 0; j < 4; ++j) {
        int row = g * 4 + j;
#pragma unroll
        for (int n = 0; n < 8; ++n) {
            int slot = n * 2 + (l15 >> 3);
            Pw[row * 128 + ((slot ^ (row & 7)) << 3) + (l15 & 7)] = (__bf16)s[n][j];
        }
    }

    bf16x8 pf[4];
#pragma unroll
    for (int kb = 0; kb < 4; ++kb)
        pf[kb] = *reinterpret_cast<const bf16x8*>(
            Pw + l15 * 128 + (((kb << 2) + g) ^ (l15 & 7)) * 8);

    __builtin_amdgcn_s_setprio(1);
#pragma unroll
    for (int kb = 0; kb < 4; ++kb) {
#pragma unroll
        for (int dt = 0; dt < 4; ++dt) {
            int rv = dt * 16 + l15;
            int slot = ((kb << 2) + g) ^ (rv & 7);
            bf16x8 vf = *reinterpret_cast<const bf16x8*>(Vc + rv * 128 + slot * 8);
            ao[dt] = __builtin_amdgcn_mfma_f32_16x16x32_bf16(pf[kb], vf, ao[dt], 0, 0, 0);
        }
    }
    __builtin_amdgcn_s_setprio(0);
}

// ================== FUSED cooperative kernel (64 KB LDS union) ==================
// ABLATION ROUND: qkv phase executed TWICE (bit-identical idempotent writes) to
// measure the qkv body time as Delta vs R16.
__global__ __launch_bounds__(256, 2) void k_fused(const float* __restrict__ x,
                                                  const float* __restrict__ topo,
                                                  const float* __restrict__ Wqkv,
                                                  const float* __restrict__ Wproj,
                                                  const float* __restrict__ Wfreq,
                                                  float* __restrict__ out,
                                                  char* __restrict__ wsb) {
    __shared__ __align__(16) char smem[65536];

    __bf16* xb     = (__bf16*)(wsb);
    __bf16* Wqkvb  = (__bf16*)(wsb + (4u << 20));
    __bf16* Wprojb = (__bf16*)(wsb + (10u << 20));
    float*  cosb   = (float*)(wsb + (12u << 20));
    float*  sinb   = (float*)(wsb + (12u << 20) + 262144);
    __bf16* Qb     = (__bf16*)(wsb + (12u << 20) + 524288);
    __bf16* Kb     = (__bf16*)(wsb + (16u << 20) + 524288);
    __bf16* Vtb    = (__bf16*)(wsb + (20u << 20) + 524288);
    __bf16* AO     = (__bf16*)(wsb + (24u << 20) + 524288);

    cg::grid_group grid = cg::this_grid();
    const int tid = threadIdx.x;
    const int bid = blockIdx.x;
    const int lane = tid & 63, w = tid >> 6;
    const int l15 = lane & 15, g = lane >> 4;

    // ---------- phase 0: setup ----------
    for (int blk = bid; blk < 6400; blk += 512)
        setup_body(blk, tid, x, Wqkv, Wproj, topo, Wfreq, xb, Wqkvb, Wprojb, cosb, sinb);
    grid.sync();

    // ---------- phase 1: qkv GEMM + RoPE — executed twice (ablation) ----------
    for (int rep = 0; rep < 2; ++rep) {
        __bf16* As = (__bf16*)smem;
        __bf16* Bs = (__bf16*)(smem + 32768);
        int m0, n0;
        qkv_map(bid, m0, n0);
        const int wr = w >> 1, wc = w & 1;
        f32x4 acc[4][3];
        gemm_coreT<128, 96, 64>(xb, Wqkvb, DMODEL, m0, n0, As, Bs, acc, tid, wr, wc, lane);
        qkv_epilogue(acc, m0, n0, wr, wc, l15, g, cosb, sinb, Qb, Kb, Vtb);
    }
    grid.sync();

    // ---------- phase 2: attention (KVBLK=128, single-buffered, balanced causal) ----------
    {
        __bf16* Ks = (__bf16*)smem;
        __bf16* Vs = (__bf16*)(smem + 16384);
        __bf16* Pw = (__bf16*)(smem + 32768) + w * 16 * 128;

        const int xc = bid & 7;
        const int t = bid >> 3;
        const int b = xc >> 2;
        const int h = (xc & 3) * 4 + (t & 3);
        const int v = t >> 2;
        const int bx = (v < 8) ? v : 23 - v;
        const int q0 = bx * 64 + w * 16;

        const __bf16* Qh = Qb + ((size_t)h * NSLOT + b * LSEQ) * DH;
        const __bf16* Kh = Kb + ((size_t)h * NSLOT + b * LSEQ) * DH;
        const __bf16* Vh = Vtb + ((size_t)h * DH) * NSLOT + b * LSEQ;

        bf16x8 qf[2];
#pragma unroll
        for (int g2 = 0; g2 < 2; ++g2)
            qf[g2] = *reinterpret_cast<const bf16x8*>(Qh + (size_t)(q0 + l15) * DH + g2 * 32 + g * 8);

        const f32x4 z = {0.f, 0.f, 0.f, 0.f};
        f32x4 ao[4];
#pragma unroll
        for (int dt = 0; dt < 4; ++dt) ao[dt] = z;
        float lsum[4] = {0.f, 0.f, 0.f, 0.f};

        const int nch = (bx >> 1) + 1;

        for (int ch = 0; ch < nch; ++ch) {
            __syncthreads();
            const int sp0 = ch * 128;
#pragma unroll
            for (int i = 0; i < 4; ++i) {
                int u = i * 256 + tid;
                {
                    int row = u >> 3, slot = u & 7, srcs = (slot ^ (row & 7)) * 8;
                    __builtin_amdgcn_global_load_lds(
                        (const __attribute__((address_space(1))) void*)(Kh + (size_t)(sp0 + row) * DH + srcs),
                        (__attribute__((address_space(3))) void*)(Ks + i * 2048 + w * 512), 16, 0, 0);
                }
                {
                    int row = u >> 4, slot = u & 15, srcs = (slot ^ (row & 7)) * 8;
                    __builtin_amdgcn_global_load_lds(
                        (const __attribute__((address_space(1))) void*)(Vh + (size_t)row * NSLOT + sp0 + srcs),
                        (__attribute__((address_space(3))) void*)(Vs + i * 2048 + w * 512), 16, 0, 0);
                }
            }
            __syncthreads();
            attn_chunk(qf, Ks, Vs, Pw, ch, nch, q0, l15, g, ao, lsum);
        }

        float lrow[4];
#pragma unroll
        for (int j = 0; j < 4; ++j) {
            float vv = lsum[j];
#pragma unroll
            for (int off = 1; off < 16; off <<= 1) vv += __shfl_xor(vv, off);
            lrow[j] = vv;
        }

#pragma unroll
        for (int dt = 0; dt < 4; ++dt)
#pragma unroll
            for (int j = 0; j < 4; ++j) {
                int q = q0 + g * 4 + j;
                AO[(size_t)(b * LSEQ + q) * DMODEL + h * 64 + dt * 16 + l15] =
                    (__bf16)(ao[dt][j] / lrow[j]);
            }
    }
    grid.sync();

    // ---------- phase 3: proj GEMM (2-D XCD chunking) ----------
    {
        __bf16* As = (__bf16*)smem;
        __bf16* Bs = (__bf16*)(smem + 32768);
        int m0, n0;
        proj_map(bid, m0, n0);
        const int wr = w >> 1, wc = w & 1;
        f32x4 acc[2][2];
        gemm_coreT<64, 64, 128>(AO, Wprojb, DMODEL, m0, n0, As, Bs, acc, tid, wr, wc, lane);

#pragma unroll
        for (int n = 0; n < 2; ++n) {
            int c = n0 + wc * 32 + n * 16 + l15;
#pragma unroll
            for (int m = 0; m < 2; ++m) {
#pragma unroll
                for (int j = 0; j < 4; ++j) {
                    int s = m0 + wr * 32 + m * 16 + g * 4 + j;
                    out[(size_t)s * DMODEL + c] = acc[m][n][j];
                }
            }
        }
    }
}

// ================== FALLBACK kernels ==================
__global__ __launch_bounds__(256) void k_setup(const float* __restrict__ x,
                                               const float* __restrict__ Wqkv,
                                               const float* __restrict__ Wproj,
                                               const float* __restrict__ topo,
                                               const float* __restrict__ Wfreq,
                                               __bf16* __restrict__ xb,
                                               __bf16* __restrict__ Wqkvb,
                                               __bf16* __restrict__ Wprojb,
                                               float* __restrict__ cosb,
                                               float* __restrict__ sinb) {
    setup_body(blockIdx.x, threadIdx.x, x, Wqkv, Wproj, topo, Wfreq,
               xb, Wqkvb, Wprojb, cosb, sinb);
}

__global__ __launch_bounds__(256, 2) void k_qkv_mfma(const __bf16* __restrict__ xb,
                                                     const __bf16* __restrict__ Wb,
                                                     const float* __restrict__ cosb,
                                                     const float* __restrict__ sinb,
                                                     __bf16* __restrict__ Qb,
                                                     __bf16* __restrict__ Kb,
                                                     __bf16* __restrict__ Vtb) {
    __shared__ __bf16 As[2][128 * 64];
    __shared__ __bf16 Bs[2][96 * 64];
    int m0, n0;
    qkv_map(blockIdx.x, m0, n0);
    const int tid = threadIdx.x, lane = tid & 63, w = tid >> 6;
    const int wr = w >> 1, wc = w & 1;
    const int l15 = lane & 15, g = lane >> 4;
    f32x4 acc[4][3];
    gemm_coreT<128, 96, 64>(xb, Wb, DMODEL, m0, n0, &As[0][0], &Bs[0][0], acc, tid, wr, wc, lane);
    qkv_epilogue(acc, m0, n0, wr, wc, l15, g, cosb, sinb, Qb, Kb, Vtb);
}

__global__ __launch_bounds__(256, 2) void k_attn9(const __bf16* __restrict__ Qg,
                                                  const __bf16* __restrict__ Kg,
                                                  const __bf16* __restrict__ Vt,
                                                  __bf16* __restrict__ AO) {
    int lin = blockIdx.x + 16 * (blockIdx.y + 16 * blockIdx.z);
    const int xc = lin & 7;
    const int t = lin >> 3;
    const int b = xc >> 2;
    const int h = (xc & 3) * 4 + (t & 3);
    const int v = t >> 2;
    const int bx = (v < 8) ? v : 23 - v;

    const int tid = threadIdx.x, w = tid >> 6, lane = tid & 63;
    const int l15 = lane & 15, g = lane >> 4;
    const int q0 = bx * 64 + w * 16;

    __shared__ __bf16 Ks[2][128 * 64];
    __shared__ __bf16 Vs[2][64 * 128];
    __shared__ __bf16 P_lds[4][16 * 128];
    __bf16* Pw = &P_lds[w][0];

    const __bf16* Qh = Qg + ((size_t)h * NSLOT + b * LSEQ) * DH;
    const __bf16* Kh = Kg + ((size_t)h * NSLOT + b * LSEQ) * DH;
    const __bf16* Vh = Vt + ((size_t)h * DH) * NSLOT + b * LSEQ;

    bf16x8 qf[2];
#pragma unroll
    for (int g2 = 0; g2 < 2; ++g2)
        qf[g2] = *reinterpret_cast<const bf16x8*>(Qh + (size_t)(q0 + l15) * DH + g2 * 32 + g * 8);

    const f32x4 z = {0.f, 0.f, 0.f, 0.f};
    f32x4 ao[4];
#pragma unroll
    for (int dt = 0; dt < 4; ++dt) ao[dt] = z;
    float lsum[4] = {0.f, 0.f, 0.f, 0.f};

    const int nch = (bx >> 1) + 1;

#pragma unroll
    for (int i = 0; i < 4; ++i) {
        int u = i * 256 + tid;
        {
            int row = u >> 3, slot = u & 7, srcs = (slot ^ (row & 7)) * 8;
            __builtin_amdgcn_global_load_lds(
                (const __attribute__((address_space(1))) void*)(Kh + (size_t)row * DH + srcs),
                (__attribute__((address_space(3))) void*)(&Ks[0][i * 2048 + w * 512]), 16, 0, 0);
        }
        {
            int row = u >> 4, slot = u & 15, srcs = (slot ^ (row & 7)) * 8;
            __builtin_amdgcn_global_load_lds(
                (const __attribute__((address_space(1))) void*)(Vh + (size_t)row * NSLOT + srcs),
                (__attribute__((address_space(3))) void*)(&Vs[0][i * 2048 + w * 512]), 16, 0, 0);
        }
    }
    __syncthreads();

    for (int ch = 0; ch < nch; ++ch) {
        const int cur = ch & 1;
        if (ch + 1 < nch) {
            const int nsp = (ch + 1) * 128;
#pragma unroll
            for (int i = 0; i < 4; ++i) {
                int u = i * 256 + tid;
                {
                    int row = u >> 3, slot = u & 7, srcs = (slot ^ (row & 7)) * 8;
                    __builtin_amdgcn_global_load_lds(
                        (const __attribute__((address_space(1))) void*)(Kh + (size_t)(nsp + row) * DH + srcs),
                        (__attribute__((address_space(3))) void*)(&Ks[1 - cur][i * 2048 + w * 512]), 16, 0, 0);
                }
                {
                    int row = u >> 4, slot = u & 15, srcs = (slot ^ (row & 7)) * 8;
                    __builtin_amdgcn_global_load_lds(
                        (const __attribute__((address_space(1))) void*)(Vh + (size_t)row * NSLOT + nsp + srcs),
                        (__attribute__((address_space(3))) void*)(&Vs[1 - cur][i * 2048 + w * 512]), 16, 0, 0);
                }
            }
        }
        attn_chunk(qf, &Ks[cur][0], &Vs[cur][0], Pw, ch, nch, q0, l15, g, ao, lsum);
        __syncthreads();
    }

    float lrow[4];
#pragma unroll
    for (int j = 0; j < 4; ++j) {
        float vv = lsum[j];
#pragma unroll
        for (int off = 1; off < 16; off <<= 1) vv += __shfl_xor(vv, off);
        lrow[j] = vv;
    }

#pragma unroll
    for (int dt = 0; dt < 4; ++dt)
#pragma unroll
        for (int j = 0; j < 4; ++j) {
            int q = q0 + g * 4 + j;
            AO[(size_t)(b * LSEQ + q) * DMODEL + h * 64 + dt * 16 + l15] =
                (__bf16)(ao[dt][j] / lrow[j]);
        }
}

__global__ __launch_bounds__(256, 2) void k_proj_mfma(const __bf16* __restrict__ AO,
                                                      const __bf16* __restrict__ Wb,
                                                      float* __restrict__ out) {
    __shared__ __bf16 As[2][64 * 128];
    __shared__ __bf16 Bs[2][64 * 128];
    int m0, n0;
    proj_map(blockIdx.x, m0, n0);
    const int tid = threadIdx.x, lane = tid & 63, w = tid >> 6;
    const int wr = w >> 1, wc = w & 1;
    const int l15 = lane & 15, g = lane >> 4;
    f32x4 acc[2][2];
    gemm_coreT<64, 64, 128>(AO, Wb, DMODEL, m0, n0, &As[0][0], &Bs[0][0], acc, tid, wr, wc, lane);

#pragma unroll
    for (int n = 0; n < 2; ++n) {
        int c = n0 + wc * 32 + n * 16 + l15;
#pragma unroll
        for (int m = 0; m < 2; ++m) {
#pragma unroll
            for (int j = 0; j < 4; ++j) {
                int s = m0 + wr * 32 + m * 16 + g * 4 + j;
                out[(size_t)s * DMODEL + c] = acc[m][n][j];
            }
        }
    }
}

extern "C" void kernel_launch(void* const* d_in, const int* in_sizes, int n_in,
                              void* d_out, int out_size, void* d_ws, size_t ws_size,
                              hipStream_t stream) {
    const float* x     = (const float*)d_in[0];
    const float* topo  = (const float*)d_in[1];
    const float* Wqkv  = (const float*)d_in[4];
    const float* Wproj = (const float*)d_in[5];
    const float* Wfreq = (const float*)d_in[6];
    float* out = (float*)d_out;
    char* wsb = (char*)d_ws;

    int coopAttr = 0, dev = 0, nb = 0;
    hipGetDevice(&dev);
    hipDeviceGetAttribute(&coopAttr, hipDeviceAttributeCooperativeLaunch, dev);
    hipOccupancyMaxActiveBlocksPerMultiprocessor(&nb, (const void*)k_fused, 256, 0);

    if (coopAttr && nb >= 2) {
        void* args[] = {(void*)&x, (void*)&topo, (void*)&Wqkv, (void*)&Wproj,
                        (void*)&Wfreq, (void*)&out, (void*)&wsb};
        hipLaunchCooperativeKernel((const void*)k_fused, dim3(512), dim3(256),
                                   args, 0, stream);
        return;
    }

    __bf16* xb     = (__bf16*)(wsb);
    __bf16* Wqkvb  = (__bf16*)(wsb + (4u << 20));
    __bf16* Wprojb = (__bf16*)(wsb + (10u << 20));
    float*  cosb   = (float*)(wsb + (12u << 20));
    float*  sinb   = (float*)(wsb + (12u << 20) + 262144);
    __bf16* Qb     = (__bf16*)(wsb + (12u << 20) + 524288);
    __bf16* Kb     = (__bf16*)(wsb + (16u << 20) + 524288);
    __bf16* Vtb    = (__bf16*)(wsb + (20u << 20) + 524288);
    __bf16* AO     = (__bf16*)(wsb + (24u << 20) + 524288);

    hipLaunchKernelGGL(k_setup, dim3(6400), dim3(256), 0, stream,
                       x, Wqkv, Wproj, topo, Wfreq, xb, Wqkvb, Wprojb, cosb, sinb);
    // ablation: qkv twice (idempotent) to match the fused path's measurement
    hipLaunchKernelGGL(k_qkv_mfma, dim3(512), dim3(256), 0, stream,
                       xb, Wqkvb, cosb, sinb, Qb, Kb, Vtb);
    hipLaunchKernelGGL(k_qkv_mfma, dim3(512), dim3(256), 0, stream,
                       xb, Wqkvb, cosb, sinb, Qb, Kb, Vtb);
    hipLaunchKernelGGL(k_attn9, dim3(LSEQ / 64, H_N, BATCH), dim3(256), 0, stream,
                       Qb, Kb, Vtb, AO);
    hipLaunchKernelGGL(k_proj_mfma, dim3(512), dim3(256), 0, stream,
                       AO, Wprojb, out);
}

// Round 18
// 60.141 us; speedup vs baseline: 1.3095x; 1.3095x over previous
//
#include <hip/hip_runtime.h>
#include <hip/hip_bf16.h>
#include <hip/hip_cooperative_groups.h>
#include <math.h>

namespace cg = cooperative_groups;

#define H_N 16
#define DH 64
#define LSEQ 1024
#define BATCH 2
#define NSLOT 2048
#define DMODEL 1024

typedef __bf16 bf16x8 __attribute__((ext_vector_type(8)));
typedef __bf16 bf16x4 __attribute__((ext_vector_type(4)));
typedef float f32x4 __attribute__((ext_vector_type(4)));

// ---------- templated MFMA GEMM core, double-buffered LDS, parametric BK ----------
template <int BM, int BN, int BK>
__device__ __forceinline__ void gemm_coreT(const __bf16* __restrict__ A,
                                           const __bf16* __restrict__ Bm,
                                           int K, int m0, int n0,
                                           __bf16* As, __bf16* Bs,
                                           f32x4 acc[BM / 32][BN / 32],
                                           int tid, int wr, int wc, int lane) {
    constexpr int MF = BM / 32, NF = BN / 32;
    constexpr int SLOTS = BK / 8;
    constexpr int RPI = 256 / SLOTS;
    constexpr int AIT = BM / RPI;
    constexpr int BIT = BN / RPI;
    const f32x4 z = {0.f, 0.f, 0.f, 0.f};
#pragma unroll
    for (int m = 0; m < MF; ++m)
#pragma unroll
        for (int n = 0; n < NF; ++n) acc[m][n] = z;

    const int l15 = lane & 15, g = lane >> 4;
    const int wv = tid >> 6;
    const int srow = tid / SLOTS, sslot = tid % SLOTS;
    const int ssrc = (sslot ^ (srow & 7)) * 8;

#pragma unroll
    for (int i = 0; i < AIT; ++i) {
        int row = i * RPI + srow;
        __builtin_amdgcn_global_load_lds(
            (const __attribute__((address_space(1))) void*)(A + (size_t)(m0 + row) * K + ssrc),
            (__attribute__((address_space(3))) void*)(As + i * 2048 + wv * 512), 16, 0, 0);
    }
#pragma unroll
    for (int i = 0; i < BIT; ++i) {
        int row = i * RPI + srow;
        __builtin_amdgcn_global_load_lds(
            (const __attribute__((address_space(1))) void*)(Bm + (size_t)(n0 + row) * K + ssrc),
            (__attribute__((address_space(3))) void*)(Bs + i * 2048 + wv * 512), 16, 0, 0);
    }
    __syncthreads();

    const int NT = K / BK;
    for (int t = 0; t < NT; ++t) {
        const int cur = t & 1;
        __bf16* Ac = As + cur * (BM * BK);
        __bf16* Bc = Bs + cur * (BN * BK);
        if (t + 1 < NT) {
            const int k0 = (t + 1) * BK;
            __bf16* An = As + (1 - cur) * (BM * BK);
            __bf16* Bn = Bs + (1 - cur) * (BN * BK);
#pragma unroll
            for (int i = 0; i < AIT; ++i) {
                int row = i * RPI + srow;
                __builtin_amdgcn_global_load_lds(
                    (const __attribute__((address_space(1))) void*)(A + (size_t)(m0 + row) * K + k0 + ssrc),
                    (__attribute__((address_space(3))) void*)(An + i * 2048 + wv * 512), 16, 0, 0);
            }
#pragma unroll
            for (int i = 0; i < BIT; ++i) {
                int row = i * RPI + srow;
                __builtin_amdgcn_global_load_lds(
                    (const __attribute__((address_space(1))) void*)(Bm + (size_t)(n0 + row) * K + k0 + ssrc),
                    (__attribute__((address_space(3))) void*)(Bn + i * 2048 + wv * 512), 16, 0, 0);
            }
        }
        __builtin_amdgcn_s_setprio(1);
#pragma unroll
        for (int kk = 0; kk < BK / 32; ++kk) {
            const int k16 = kk * 4 + g;
            bf16x8 af[MF], bfr[NF];
#pragma unroll
            for (int m = 0; m < MF; ++m) {
                int row = wr * (BM / 2) + m * 16 + l15;
                int slot = k16 ^ (row & 7);
                af[m] = *reinterpret_cast<const bf16x8*>(Ac + row * BK + slot * 8);
            }
#pragma unroll
            for (int n = 0; n < NF; ++n) {
                int col = wc * (BN / 2) + n * 16 + l15;
                int slot = k16 ^ (col & 7);
                bfr[n] = *reinterpret_cast<const bf16x8*>(Bc + col * BK + slot * 8);
            }
#pragma unroll
            for (int m = 0; m < MF; ++m)
#pragma unroll
                for (int n = 0; n < NF; ++n)
                    acc[m][n] = __builtin_amdgcn_mfma_f32_16x16x32_bf16(af[m], bfr[n], acc[m][n], 0, 0, 0);
        }
        __builtin_amdgcn_s_setprio(0);
        __syncthreads();
    }
}

// ---------- shared device helpers ----------
__device__ __forceinline__ void setup_body(int blk, int tid,
                                           const float* x, const float* Wqkv, const float* Wproj,
                                           const float* topo, const float* Wfreq,
                                           __bf16* xb, __bf16* Wqkvb, __bf16* Wprojb,
                                           float* cosb, float* sinb) {
    if (blk < 6144) {
        const float* in;
        __bf16* ob;
        int base;
        if (blk < 2048)      { in = x;     ob = xb;     base = blk; }
        else if (blk < 5120) { in = Wqkv;  ob = Wqkvb;  base = blk - 2048; }
        else                 { in = Wproj; ob = Wprojb; base = blk - 5120; }
        int i = (base * 256 + tid) * 4;
        float4 v = *reinterpret_cast<const float4*>(in + i);
        struct B4 { __bf16 a, b, c, d; };
        B4 o{(__bf16)v.x, (__bf16)v.y, (__bf16)v.z, (__bf16)v.w};
        *reinterpret_cast<B4*>(ob + i) = o;
    } else {
        int s = (blk - 6144) * 8 + (tid >> 5);
        int j = tid & 31;
        float f = 0.f;
#pragma unroll
        for (int t = 0; t < 8; ++t) f += topo[s * 8 + t] * Wfreq[j * 8 + t];
        cosb[s * 32 + j] = cosf(f);
        sinb[s * 32 + j] = sinf(f);
    }
}

// 2-D XCD-chunked block mappings
__device__ __forceinline__ void qkv_map(int bid, int& m0, int& n0) {
    const int xcd = bid & 7, t = bid >> 3;
    m0 = ((xcd & 1) * 8 + (t & 7)) * 128;
    n0 = ((xcd >> 1) * 8 + (t >> 3)) * 96;
}
__device__ __forceinline__ void proj_map(int bid, int& m0, int& n0) {
    const int xcd = bid & 7, t = bid >> 3;
    m0 = ((xcd & 3) * 8 + (t & 7)) * 64;
    n0 = ((xcd >> 2) * 8 + (t >> 3)) * 64;
}

__device__ __forceinline__ void qkv_epilogue(f32x4 acc[4][3], int m0, int n0,
                                             int wr, int wc, int l15, int g,
                                             const float* cosb, const float* sinb,
                                             __bf16* Qb, __bf16* Kb, __bf16* Vtb) {
    const int rbase = m0 + wr * 64;
#pragma unroll
    for (int n = 0; n < 3; ++n) {
        int c = n0 + wc * 48 + n * 16 + l15;
        int part = c >> 10, h = (c >> 6) & 15, d = c & 63, jj = d >> 1;
#pragma unroll
        for (int m = 0; m < 4; ++m) {
            int sbase = rbase + m * 16 + g * 4;
            if (part < 2) {
                __bf16* dst = (part == 0) ? Qb : Kb;
#pragma unroll
                for (int j = 0; j < 4; ++j) {
                    int s = sbase + j;
                    float v = acc[m][n][j];
                    float partner = __shfl_xor(v, 1);
                    float cs = cosb[s * 32 + jj], sn = sinb[s * 32 + jj];
                    float outv = (d & 1) ? fmaf(v, cs, partner * sn) : fmaf(v, cs, -partner * sn);
                    dst[((size_t)h * NSLOT + s) * DH + d] = (__bf16)outv;
                }
            } else {
                bf16x4 pk;
#pragma unroll
                for (int j = 0; j < 4; ++j) pk[j] = (__bf16)acc[m][n][j];
                *reinterpret_cast<bf16x4*>(&Vtb[((size_t)h * DH + d) * NSLOT + sbase]) = pk;
            }
        }
    }
}

// attention chunk compute (KVBLK=128)
__device__ __forceinline__ void attn_chunk(const bf16x8 qf[2], __bf16* Kc, __bf16* Vc,
                                           __bf16* Pw, int ch, int nch, int q0,
                                           int l15, int g, f32x4 ao[4], float lsum[4]) {
    const f32x4 z = {0.f, 0.f, 0.f, 0.f};
    f32x4 s[8];
#pragma unroll
    for (int n = 0; n < 8; ++n) s[n] = z;
    __builtin_amdgcn_s_setprio(1);
#pragma unroll
    for (int g2 = 0; g2 < 2; ++g2) {
#pragma unroll
        for (int n = 0; n < 8; ++n) {
            int r = n * 16 + l15;
            int slot = ((g2 << 2) + g) ^ (r & 7);
            bf16x8 kf = *reinterpret_cast<const bf16x8*>(Kc + r * 64 + slot * 8);
            s[n] = __builtin_amdgcn_mfma_f32_16x16x32_bf16(qf[g2], kf, s[n], 0, 0, 0);
        }
    }
    __builtin_amdgcn_s_setprio(0);

    const bool last = (ch == nch - 1);
    const int sp0 = ch * 128;
#pragma unroll
    for (int n = 0; n < 8; ++n) {
        int key = sp0 + n * 16 + l15;
#pragma unroll
        for (int j = 0; j < 4; ++j) {
            float sc = s[n][j] * 0.125f;
            if (last && key > q0 + g * 4 + j) sc = -INFINITY;
            float p = __expf(sc);
            s[n][j] = p;
            lsum[j] += p;
        }
    }

#pragma unroll
    for (int j = 0; j < 4; ++j) {
        int row = g * 4 + j;
#pragma unroll
        for (int n = 0; n < 8; ++n) {
            int slot = n * 2 + (l15 >> 3);
            Pw[row * 128 + ((slot ^ (row & 7)) << 3) + (l15 & 7)] = (__bf16)s[n][j];
        }
    }

    bf16x8 pf[4];
#pragma unroll
    for (int kb = 0; kb < 4; ++kb)
        pf[kb] = *reinterpret_cast<const bf16x8*>(
            Pw + l15 * 128 + (((kb << 2) + g) ^ (l15 & 7)) * 8);

    __builtin_amdgcn_s_setprio(1);
#pragma unroll
    for (int kb = 0; kb < 4; ++kb) {
#pragma unroll
        for (int dt = 0; dt < 4; ++dt) {
            int rv = dt * 16 + l15;
            int slot = ((kb << 2) + g) ^ (rv & 7);
            bf16x8 vf = *reinterpret_cast<const bf16x8*>(Vc + rv * 128 + slot * 8);
            ao[dt] = __builtin_amdgcn_mfma_f32_16x16x32_bf16(pf[kb], vf, ao[dt], 0, 0, 0);
        }
    }
    __builtin_amdgcn_s_setprio(0);
}

// ================== FUSED cooperative kernel (64 KB LDS union) ==================
// SYNC-COST PROBE: each phase boundary runs grid.sync() x3 (semantic no-ops).
// Delta vs R16 (60.4us) / 6 = per-sync cost.
__global__ __launch_bounds__(256, 2) void k_fused(const float* __restrict__ x,
                                                  const float* __restrict__ topo,
                                                  const float* __restrict__ Wqkv,
                                                  const float* __restrict__ Wproj,
                                                  const float* __restrict__ Wfreq,
                                                  float* __restrict__ out,
                                                  char* __restrict__ wsb) {
    __shared__ __align__(16) char smem[65536];

    __bf16* xb     = (__bf16*)(wsb);
    __bf16* Wqkvb  = (__bf16*)(wsb + (4u << 20));
    __bf16* Wprojb = (__bf16*)(wsb + (10u << 20));
    float*  cosb   = (float*)(wsb + (12u << 20));
    float*  sinb   = (float*)(wsb + (12u << 20) + 262144);
    __bf16* Qb     = (__bf16*)(wsb + (12u << 20) + 524288);
    __bf16* Kb     = (__bf16*)(wsb + (16u << 20) + 524288);
    __bf16* Vtb    = (__bf16*)(wsb + (20u << 20) + 524288);
    __bf16* AO     = (__bf16*)(wsb + (24u << 20) + 524288);

    cg::grid_group grid = cg::this_grid();
    const int tid = threadIdx.x;
    const int bid = blockIdx.x;
    const int lane = tid & 63, w = tid >> 6;
    const int l15 = lane & 15, g = lane >> 4;

    // ---------- phase 0: setup ----------
    for (int blk = bid; blk < 6400; blk += 512)
        setup_body(blk, tid, x, Wqkv, Wproj, topo, Wfreq, xb, Wqkvb, Wprojb, cosb, sinb);
    grid.sync(); grid.sync(); grid.sync();   // probe: 3x

    // ---------- phase 1: qkv GEMM + RoPE ----------
    {
        __bf16* As = (__bf16*)smem;
        __bf16* Bs = (__bf16*)(smem + 32768);
        int m0, n0;
        qkv_map(bid, m0, n0);
        const int wr = w >> 1, wc = w & 1;
        f32x4 acc[4][3];
        gemm_coreT<128, 96, 64>(xb, Wqkvb, DMODEL, m0, n0, As, Bs, acc, tid, wr, wc, lane);
        qkv_epilogue(acc, m0, n0, wr, wc, l15, g, cosb, sinb, Qb, Kb, Vtb);
    }
    grid.sync(); grid.sync(); grid.sync();   // probe: 3x

    // ---------- phase 2: attention (KVBLK=128, single-buffered, balanced causal) ----------
    {
        __bf16* Ks = (__bf16*)smem;
        __bf16* Vs = (__bf16*)(smem + 16384);
        __bf16* Pw = (__bf16*)(smem + 32768) + w * 16 * 128;

        const int xc = bid & 7;
        const int t = bid >> 3;
        const int b = xc >> 2;
        const int h = (xc & 3) * 4 + (t & 3);
        const int v = t >> 2;
        const int bx = (v < 8) ? v : 23 - v;
        const int q0 = bx * 64 + w * 16;

        const __bf16* Qh = Qb + ((size_t)h * NSLOT + b * LSEQ) * DH;
        const __bf16* Kh = Kb + ((size_t)h * NSLOT + b * LSEQ) * DH;
        const __bf16* Vh = Vtb + ((size_t)h * DH) * NSLOT + b * LSEQ;

        bf16x8 qf[2];
#pragma unroll
        for (int g2 = 0; g2 < 2; ++g2)
            qf[g2] = *reinterpret_cast<const bf16x8*>(Qh + (size_t)(q0 + l15) * DH + g2 * 32 + g * 8);

        const f32x4 z = {0.f, 0.f, 0.f, 0.f};
        f32x4 ao[4];
#pragma unroll
        for (int dt = 0; dt < 4; ++dt) ao[dt] = z;
        float lsum[4] = {0.f, 0.f, 0.f, 0.f};

        const int nch = (bx >> 1) + 1;

        for (int ch = 0; ch < nch; ++ch) {
            __syncthreads();
            const int sp0 = ch * 128;
#pragma unroll
            for (int i = 0; i < 4; ++i) {
                int u = i * 256 + tid;
                {
                    int row = u >> 3, slot = u & 7, srcs = (slot ^ (row & 7)) * 8;
                    __builtin_amdgcn_global_load_lds(
                        (const __attribute__((address_space(1))) void*)(Kh + (size_t)(sp0 + row) * DH + srcs),
                        (__attribute__((address_space(3))) void*)(Ks + i * 2048 + w * 512), 16, 0, 0);
                }
                {
                    int row = u >> 4, slot = u & 15, srcs = (slot ^ (row & 7)) * 8;
                    __builtin_amdgcn_global_load_lds(
                        (const __attribute__((address_space(1))) void*)(Vh + (size_t)row * NSLOT + sp0 + srcs),
                        (__attribute__((address_space(3))) void*)(Vs + i * 2048 + w * 512), 16, 0, 0);
                }
            }
            __syncthreads();
            attn_chunk(qf, Ks, Vs, Pw, ch, nch, q0, l15, g, ao, lsum);
        }

        float lrow[4];
#pragma unroll
        for (int j = 0; j < 4; ++j) {
            float vv = lsum[j];
#pragma unroll
            for (int off = 1; off < 16; off <<= 1) vv += __shfl_xor(vv, off);
            lrow[j] = vv;
        }

#pragma unroll
        for (int dt = 0; dt < 4; ++dt)
#pragma unroll
            for (int j = 0; j < 4; ++j) {
                int q = q0 + g * 4 + j;
                AO[(size_t)(b * LSEQ + q) * DMODEL + h * 64 + dt * 16 + l15] =
                    (__bf16)(ao[dt][j] / lrow[j]);
            }
    }
    grid.sync(); grid.sync(); grid.sync();   // probe: 3x

    // ---------- phase 3: proj GEMM ----------
    {
        __bf16* As = (__bf16*)smem;
        __bf16* Bs = (__bf16*)(smem + 32768);
        int m0, n0;
        proj_map(bid, m0, n0);
        const int wr = w >> 1, wc = w & 1;
        f32x4 acc[2][2];
        gemm_coreT<64, 64, 128>(AO, Wprojb, DMODEL, m0, n0, As, Bs, acc, tid, wr, wc, lane);

#pragma unroll
        for (int n = 0; n < 2; ++n) {
            int c = n0 + wc * 32 + n * 16 + l15;
#pragma unroll
            for (int m = 0; m < 2; ++m) {
#pragma unroll
                for (int j = 0; j < 4; ++j) {
                    int s = m0 + wr * 32 + m * 16 + g * 4 + j;
                    out[(size_t)s * DMODEL + c] = acc[m][n][j];
                }
            }
        }
    }
}

// ================== FALLBACK kernels (R13/R16 proven path) ==================
__global__ __launch_bounds__(256) void k_setup(const float* __restrict__ x,
                                               const float* __restrict__ Wqkv,
                                               const float* __restrict__ Wproj,
                                               const float* __restrict__ topo,
                                               const float* __restrict__ Wfreq,
                                               __bf16* __restrict__ xb,
                                               __bf16* __restrict__ Wqkvb,
                                               __bf16* __restrict__ Wprojb,
                                               float* __restrict__ cosb,
                                               float* __restrict__ sinb) {
    setup_body(blockIdx.x, threadIdx.x, x, Wqkv, Wproj, topo, Wfreq,
               xb, Wqkvb, Wprojb, cosb, sinb);
}

__global__ __launch_bounds__(256, 2) void k_qkv_mfma(const __bf16* __restrict__ xb,
                                                     const __bf16* __restrict__ Wb,
                                                     const float* __restrict__ cosb,
                                                     const float* __restrict__ sinb,
                                                     __bf16* __restrict__ Qb,
                                                     __bf16* __restrict__ Kb,
                                                     __bf16* __restrict__ Vtb) {
    __shared__ __bf16 As[2][128 * 64];
    __shared__ __bf16 Bs[2][96 * 64];
    int m0, n0;
    qkv_map(blockIdx.x, m0, n0);
    const int tid = threadIdx.x, lane = tid & 63, w = tid >> 6;
    const int wr = w >> 1, wc = w & 1;
    const int l15 = lane & 15, g = lane >> 4;
    f32x4 acc[4][3];
    gemm_coreT<128, 96, 64>(xb, Wb, DMODEL, m0, n0, &As[0][0], &Bs[0][0], acc, tid, wr, wc, lane);
    qkv_epilogue(acc, m0, n0, wr, wc, l15, g, cosb, sinb, Qb, Kb, Vtb);
}

__global__ __launch_bounds__(256, 2) void k_attn9(const __bf16* __restrict__ Qg,
                                                  const __bf16* __restrict__ Kg,
                                                  const __bf16* __restrict__ Vt,
                                                  __bf16* __restrict__ AO) {
    int lin = blockIdx.x + 16 * (blockIdx.y + 16 * blockIdx.z);
    const int xc = lin & 7;
    const int t = lin >> 3;
    const int b = xc >> 2;
    const int h = (xc & 3) * 4 + (t & 3);
    const int v = t >> 2;
    const int bx = (v < 8) ? v : 23 - v;

    const int tid = threadIdx.x, w = tid >> 6, lane = tid & 63;
    const int l15 = lane & 15, g = lane >> 4;
    const int q0 = bx * 64 + w * 16;

    __shared__ __bf16 Ks[2][128 * 64];
    __shared__ __bf16 Vs[2][64 * 128];
    __shared__ __bf16 P_lds[4][16 * 128];
    __bf16* Pw = &P_lds[w][0];

    const __bf16* Qh = Qg + ((size_t)h * NSLOT + b * LSEQ) * DH;
    const __bf16* Kh = Kg + ((size_t)h * NSLOT + b * LSEQ) * DH;
    const __bf16* Vh = Vt + ((size_t)h * DH) * NSLOT + b * LSEQ;

    bf16x8 qf[2];
#pragma unroll
    for (int g2 = 0; g2 < 2; ++g2)
        qf[g2] = *reinterpret_cast<const bf16x8*>(Qh + (size_t)(q0 + l15) * DH + g2 * 32 + g * 8);

    const f32x4 z = {0.f, 0.f, 0.f, 0.f};
    f32x4 ao[4];
#pragma unroll
    for (int dt = 0; dt < 4; ++dt) ao[dt] = z;
    float lsum[4] = {0.f, 0.f, 0.f, 0.f};

    const int nch = (bx >> 1) + 1;

#pragma unroll
    for (int i = 0; i < 4; ++i) {
        int u = i * 256 + tid;
        {
            int row = u >> 3, slot = u & 7, srcs = (slot ^ (row & 7)) * 8;
            __builtin_amdgcn_global_load_lds(
                (const __attribute__((address_space(1))) void*)(Kh + (size_t)row * DH + srcs),
                (__attribute__((address_space(3))) void*)(&Ks[0][i * 2048 + w * 512]), 16, 0, 0);
        }
        {
            int row = u >> 4, slot = u & 15, srcs = (slot ^ (row & 7)) * 8;
            __builtin_amdgcn_global_load_lds(
                (const __attribute__((address_space(1))) void*)(Vh + (size_t)row * NSLOT + srcs),
                (__attribute__((address_space(3))) void*)(&Vs[0][i * 2048 + w * 512]), 16, 0, 0);
        }
    }
    __syncthreads();

    for (int ch = 0; ch < nch; ++ch) {
        const int cur = ch & 1;
        if (ch + 1 < nch) {
            const int nsp = (ch + 1) * 128;
#pragma unroll
            for (int i = 0; i < 4; ++i) {
                int u = i * 256 + tid;
                {
                    int row = u >> 3, slot = u & 7, srcs = (slot ^ (row & 7)) * 8;
                    __builtin_amdgcn_global_load_lds(
                        (const __attribute__((address_space(1))) void*)(Kh + (size_t)(nsp + row) * DH + srcs),
                        (__attribute__((address_space(3))) void*)(&Ks[1 - cur][i * 2048 + w * 512]), 16, 0, 0);
                }
                {
                    int row = u >> 4, slot = u & 15, srcs = (slot ^ (row & 7)) * 8;
                    __builtin_amdgcn_global_load_lds(
                        (const __attribute__((address_space(1))) void*)(Vh + (size_t)row * NSLOT + nsp + srcs),
                        (__attribute__((address_space(3))) void*)(&Vs[1 - cur][i * 2048 + w * 512]), 16, 0, 0);
                }
            }
        }
        attn_chunk(qf, &Ks[cur][0], &Vs[cur][0], Pw, ch, nch, q0, l15, g, ao, lsum);
        __syncthreads();
    }

    float lrow[4];
#pragma unroll
    for (int j = 0; j < 4; ++j) {
        float vv = lsum[j];
#pragma unroll
        for (int off = 1; off < 16; off <<= 1) vv += __shfl_xor(vv, off);
        lrow[j] = vv;
    }

#pragma unroll
    for (int dt = 0; dt < 4; ++dt)
#pragma unroll
        for (int j = 0; j < 4; ++j) {
            int q = q0 + g * 4 + j;
            AO[(size_t)(b * LSEQ + q) * DMODEL + h * 64 + dt * 16 + l15] =
                (__bf16)(ao[dt][j] / lrow[j]);
        }
}

__global__ __launch_bounds__(256, 2) void k_proj_mfma(const __bf16* __restrict__ AO,
                                                      const __bf16* __restrict__ Wb,
                                                      float* __restrict__ out) {
    __shared__ __bf16 As[2][64 * 128];
    __shared__ __bf16 Bs[2][64 * 128];
    int m0, n0;
    proj_map(blockIdx.x, m0, n0);
    const int tid = threadIdx.x, lane = tid & 63, w = tid >> 6;
    const int wr = w >> 1, wc = w & 1;
    const int l15 = lane & 15, g = lane >> 4;
    f32x4 acc[2][2];
    gemm_coreT<64, 64, 128>(AO, Wb, DMODEL, m0, n0, &As[0][0], &Bs[0][0], acc, tid, wr, wc, lane);

#pragma unroll
    for (int n = 0; n < 2; ++n) {
        int c = n0 + wc * 32 + n * 16 + l15;
#pragma unroll
        for (int m = 0; m < 2; ++m) {
#pragma unroll
            for (int j = 0; j < 4; ++j) {
                int s = m0 + wr * 32 + m * 16 + g * 4 + j;
                out[(size_t)s * DMODEL + c] = acc[m][n][j];
            }
        }
    }
}

extern "C" void kernel_launch(void* const* d_in, const int* in_sizes, int n_in,
                              void* d_out, int out_size, void* d_ws, size_t ws_size,
                              hipStream_t stream) {
    const float* x     = (const float*)d_in[0];
    const float* topo  = (const float*)d_in[1];
    const float* Wqkv  = (const float*)d_in[4];
    const float* Wproj = (const float*)d_in[5];
    const float* Wfreq = (const float*)d_in[6];
    float* out = (float*)d_out;
    char* wsb = (char*)d_ws;

    int coopAttr = 0, dev = 0, nb = 0;
    hipGetDevice(&dev);
    hipDeviceGetAttribute(&coopAttr, hipDeviceAttributeCooperativeLaunch, dev);
    hipOccupancyMaxActiveBlocksPerMultiprocessor(&nb, (const void*)k_fused, 256, 0);

    if (coopAttr && nb >= 2) {
        void* args[] = {(void*)&x, (void*)&topo, (void*)&Wqkv, (void*)&Wproj,
                        (void*)&Wfreq, (void*)&out, (void*)&wsb};
        hipLaunchCooperativeKernel((const void*)k_fused, dim3(512), dim3(256),
                                   args, 0, stream);
        return;
    }

    __bf16* xb     = (__bf16*)(wsb);
    __bf16* Wqkvb  = (__bf16*)(wsb + (4u << 20));
    __bf16* Wprojb = (__bf16*)(wsb + (10u << 20));
    float*  cosb   = (float*)(wsb + (12u << 20));
    float*  sinb   = (float*)(wsb + (12u << 20) + 262144);
    __bf16* Qb     = (__bf16*)(wsb + (12u << 20) + 524288);
    __bf16* Kb     = (__bf16*)(wsb + (16u << 20) + 524288);
    __bf16* Vtb    = (__bf16*)(wsb + (20u << 20) + 524288);
    __bf16* AO     = (__bf16*)(wsb + (24u << 20) + 524288);

    hipLaunchKernelGGL(k_setup, dim3(6400), dim3(256), 0, stream,
                       x, Wqkv, Wproj, topo, Wfreq, xb, Wqkvb, Wprojb, cosb, sinb);
    hipLaunchKernelGGL(k_qkv_mfma, dim3(512), dim3(256), 0, stream,
                       xb, Wqkvb, cosb, sinb, Qb, Kb, Vtb);
    hipLaunchKernelGGL(k_attn9, dim3(LSEQ / 64, H_N, BATCH), dim3(256), 0, stream,
                       Qb, Kb, Vtb, AO);
    hipLaunchKernelGGL(k_proj_mfma, dim3(512), dim3(256), 0, stream,
                       AO, Wprojb, out);
}